// Round 1
// baseline (2022.400 us; speedup 1.0000x reference)
//
#include <hip/hip_runtime.h>

#define FIR_LEN 8192
#define NFREQ   4097         // FIR_LEN/2 + 1
#define L_SIG   524288
#define NB      8
#define NC      2
#define NK      6
#define TWO_PI  6.283185307179586f

// ---------------------------------------------------------------------------
// K1: cascade frequency response H[b][f] = prod_k (b0+b1 w+b2 w^2)/(1+a1 w+a2 w^2),
//     w = e^{-i 2pi f / 8192}, f = 0..4096
// ---------------------------------------------------------------------------
__global__ void k_freqresp(const float* __restrict__ Bs,
                           const float* __restrict__ A1p,
                           const float* __restrict__ A2p,
                           float2* __restrict__ H) {
  __shared__ float sb0[NK], sb1[NK], sb2[NK], sa1[NK], sa2[NK];
  const int b = blockIdx.x, tid = threadIdx.x;
  if (tid < NK) {
    sb0[tid] = Bs[(b*NK+tid)*3+0];
    sb1[tid] = Bs[(b*NK+tid)*3+1];
    sb2[tid] = Bs[(b*NK+tid)*3+2];
    float a1 = 2.0f * tanhf(A1p[b*NK+tid]);
    float aa = fabsf(a1);
    sa1[tid] = a1;
    sa2[tid] = ((2.0f - aa) * tanhf(A2p[b*NK+tid]) + aa) * 0.5f;
  }
  __syncthreads();
  for (int f = tid; f < NFREQ; f += blockDim.x) {
    float th = (float)f * (TWO_PI / FIR_LEN);
    float s1, c1;
    sincosf(th, &s1, &c1);
    float c2 = c1*c1 - s1*s1, s2 = 2.0f*s1*c1;   // double angle, exact enough
    float hr = 1.0f, hi = 0.0f;
#pragma unroll
    for (int k = 0; k < NK; ++k) {
      // numerator / denominator at w = (c1, -s1)
      float nr = sb0[k] + sb1[k]*c1 + sb2[k]*c2;
      float ni = -(sb1[k]*s1 + sb2[k]*s2);
      float dr = 1.0f + sa1[k]*c1 + sa2[k]*c2;
      float di = -(sa1[k]*s1 + sa2[k]*s2);
      float inv = 1.0f / (dr*dr + di*di);
      float rr = (nr*dr + ni*di) * inv;
      float ri = (ni*dr - nr*di) * inv;
      float t  = hr*rr - hi*ri;
      hi = hr*ri + hi*rr;
      hr = t;
    }
    H[b*NFREQ+f] = make_float2(hr, hi);
  }
}

// ---------------------------------------------------------------------------
// K2: fir[b][n] = irfft(H[b], 8192)[n]
//     = (1/N) [ H0 + 2*sum_{f=1}^{4095} (Hr cos(2pi f n/N) - Hi sin(2pi f n/N))
//               + Hr[4096]*(-1)^n ]
// 4 independent rotation streams (ILP), exact-phase resync every 128 steps.
// ---------------------------------------------------------------------------
__global__ void k_irfft(const float2* __restrict__ H, float* __restrict__ fir) {
  __shared__ float2 Hs[NFREQ];
  const int b = blockIdx.x >> 5, nb = blockIdx.x & 31, tid = threadIdx.x;
  for (int i = tid; i < NFREQ; i += 256) Hs[i] = H[b*NFREQ+i];
  __syncthreads();
  const int n = nb*256 + tid;
  float sd, cd;
  sincosf((float)n * (TWO_PI / FIR_LEN), &sd, &cd);
  float c[4], s[4], acc[4] = {0.f, 0.f, 0.f, 0.f};
  for (int m = 0; m < 1024; ++m) {
    if ((m & 127) == 0) {        // resync all 4 streams with exact integer phase
#pragma unroll
      for (int q = 0; q < 4; ++q) {
        int f = 1 + q*1024 + m;
        float ph = (float)((n*f) & (FIR_LEN-1)) * (TWO_PI / FIR_LEN);
        sincosf(ph, &s[q], &c[q]);
      }
    }
#pragma unroll
    for (int q = 0; q < 4; ++q) {
      int f = 1 + q*1024 + m;
      if (q < 3 || m < 1023) {   // stream 3 stops at f=4095; f=4096 handled below
        float2 h = Hs[f];
        acc[q] = fmaf(h.x, c[q], acc[q]);
        acc[q] = fmaf(-h.y, s[q], acc[q]);
      }
      float t = c[q]*cd - s[q]*sd;   // rotate e^{i 2pi n/N}
      s[q] = s[q]*cd + c[q]*sd;
      c[q] = t;
    }
  }
  float par = (n & 1) ? -1.0f : 1.0f;
  float v = Hs[0].x + Hs[4096].x * par + 2.0f*(acc[0]+acc[1]+acc[2]+acc[3]);
  fir[b*FIR_LEN + n] = v * (1.0f / FIR_LEN);
}

// ---------------------------------------------------------------------------
// K3: y[b,c,t] = sum_{tau=0}^{8191} fir[b][tau] * x[b,c,t-tau]  (causal)
// Tile = 4096 outputs/block, 16 consecutive outputs/thread.
// x window staged in LDS with +1-per-32 pad (kills the stride-8 bank conflict);
// fir staged in 4 x 8KB chunks. Circular 16-register x window: with
// #pragma unroll 16 every index is compile-time -> no register shuffling.
// ---------------------------------------------------------------------------
#define TILE    4096
#define HIST    (FIR_LEN - 1)        // 8191
#define WIN     (HIST + TILE)        // 12287
#define XPAD(i) ((i) + ((i) >> 5))

__global__ __launch_bounds__(256) void k_conv(const float* __restrict__ x,
                                              const float* __restrict__ fir,
                                              float* __restrict__ y) {
  __shared__ float fir_s[2048];
  __shared__ float xs[WIN + WIN/32 + 2];   // 12672 floats = 49.5 KB
  const int tid  = threadIdx.x;
  const int tile = blockIdx.x & 127;       // 128 tiles per (b,c)
  const int bc   = blockIdx.x >> 7;        // 0..15
  const int b    = bc >> 1;
  const long base = (long)bc * L_SIG;
  const int t0 = tile * TILE;

  // stage x window: local k <-> global t0 - 8191 + k
  for (int k = tid; k < WIN; k += 256) {
    int g = t0 - HIST + k;
    xs[XPAD(k)] = (g >= 0) ? x[base + g] : 0.0f;
  }

  float acc[16];
  float w[16];
#pragma unroll
  for (int i = 0; i < 16; ++i) acc[i] = 0.0f;
  const int ob = 16 * tid;                 // this thread's outputs t0+ob .. +15
  __syncthreads();
#pragma unroll
  for (int i = 0; i < 16; ++i) w[i] = xs[XPAD(HIST + ob + i)];  // x[o+i] at tau=0
  const int a0 = HIST - 1 + ob;

  for (int cc = 0; cc < 4; ++cc) {
    __syncthreads();                       // previous fir chunk fully consumed
    const float4* f4 = (const float4*)(fir + (b*FIR_LEN + cc*2048));
    float4* fs4 = (float4*)fir_s;
    for (int i = tid; i < 512; i += 256) fs4[i] = f4[i];
    __syncthreads();
#pragma unroll 16
    for (int t2 = 0; t2 < 2048; ++t2) {
      const int tau = cc*2048 + t2;        // tau ≡ t2 (mod 16)
      const float f = fir_s[t2];           // wave-uniform broadcast read
#pragma unroll
      for (int i = 0; i < 16; ++i)
        acc[i] = fmaf(f, w[(i - t2) & 15], acc[i]);
      int g = a0 - tau;                    // next window element x[o - tau - 1]
      if (g < 0) g = 0;                    // clamped read only on dead last iter
      w[(-1 - t2) & 15] = xs[XPAD(g)];
    }
  }

  const long yb = base + t0 + ob;
#pragma unroll
  for (int i = 0; i < 16; ++i) y[yb + i] = acc[i];
}

// ---------------------------------------------------------------------------
extern "C" void kernel_launch(void* const* d_in, const int* in_sizes, int n_in,
                              void* d_out, int out_size, void* d_ws, size_t ws_size,
                              hipStream_t stream) {
  const float* x   = (const float*)d_in[0];
  const float* Bs  = (const float*)d_in[1];
  const float* A1p = (const float*)d_in[2];
  const float* A2p = (const float*)d_in[3];
  float* y = (float*)d_out;

  float2* H  = (float2*)d_ws;                              // 8*4097 float2
  float*  fir = (float*)d_ws + 2*(size_t)NB*NFREQ;         // 8*8192 f32 (16B aligned)

  k_freqresp<<<NB, 256, 0, stream>>>(Bs, A1p, A2p, H);
  k_irfft<<<NB*32, 256, 0, stream>>>(H, fir);
  k_conv<<<NB*NC*(L_SIG/TILE), 256, 0, stream>>>(x, fir, y);
}

// Round 4
// 403.054 us; speedup vs baseline: 5.0177x; 5.0177x over previous
//
#include <hip/hip_runtime.h>

#define FIR_LEN 8192
#define NFREQ   4097         // FIR_LEN/2 + 1
#define L_SIG   524288
#define NB      8
#define NC      2
#define NK      6
#define TWO_PI  6.283185307179586f

typedef __attribute__((ext_vector_type(8))) short bf16x8;
typedef __attribute__((ext_vector_type(4))) float f32x4;

__device__ inline short f2bf(float f) {
  union { float f; unsigned u; } v; v.f = f;
  unsigned u = v.u;
  unsigned r = (u + 0x7fffu + ((u >> 16) & 1u)) >> 16;   // RNE
  return (short)r;
}

// ---------------------------------------------------------------------------
// K1: cascade frequency response H[b][f] (verified round 1)
// ---------------------------------------------------------------------------
__global__ void k_freqresp(const float* __restrict__ Bs,
                           const float* __restrict__ A1p,
                           const float* __restrict__ A2p,
                           float2* __restrict__ H) {
  __shared__ float sb0[NK], sb1[NK], sb2[NK], sa1[NK], sa2[NK];
  const int b = blockIdx.x, tid = threadIdx.x;
  if (tid < NK) {
    sb0[tid] = Bs[(b*NK+tid)*3+0];
    sb1[tid] = Bs[(b*NK+tid)*3+1];
    sb2[tid] = Bs[(b*NK+tid)*3+2];
    float a1 = 2.0f * tanhf(A1p[b*NK+tid]);
    float aa = fabsf(a1);
    sa1[tid] = a1;
    sa2[tid] = ((2.0f - aa) * tanhf(A2p[b*NK+tid]) + aa) * 0.5f;
  }
  __syncthreads();
  for (int f = tid; f < NFREQ; f += blockDim.x) {
    float th = (float)f * (TWO_PI / FIR_LEN);
    float s1, c1;
    sincosf(th, &s1, &c1);
    float c2 = c1*c1 - s1*s1, s2 = 2.0f*s1*c1;
    float hr = 1.0f, hi = 0.0f;
#pragma unroll
    for (int k = 0; k < NK; ++k) {
      float nr = sb0[k] + sb1[k]*c1 + sb2[k]*c2;
      float ni = -(sb1[k]*s1 + sb2[k]*s2);
      float dr = 1.0f + sa1[k]*c1 + sa2[k]*c2;
      float di = -(sa1[k]*s1 + sa2[k]*s2);
      float inv = 1.0f / (dr*dr + di*di);
      float rr = (nr*dr + ni*di) * inv;
      float ri = (ni*dr - nr*di) * inv;
      float t  = hr*rr - hi*ri;
      hi = hr*ri + hi*rr;
      hr = t;
    }
    H[b*NFREQ+f] = make_float2(hr, hi);
  }
}

// ---------------------------------------------------------------------------
// K2: fir = irfft(H, 8192) (verified round 1)
// ---------------------------------------------------------------------------
__global__ void k_irfft(const float2* __restrict__ H, float* __restrict__ fir) {
  __shared__ float2 Hs[NFREQ];
  const int b = blockIdx.x >> 5, nb = blockIdx.x & 31, tid = threadIdx.x;
  for (int i = tid; i < NFREQ; i += 256) Hs[i] = H[b*NFREQ+i];
  __syncthreads();
  const int n = nb*256 + tid;
  float sd, cd;
  sincosf((float)n * (TWO_PI / FIR_LEN), &sd, &cd);
  float c[4], s[4], acc[4] = {0.f, 0.f, 0.f, 0.f};
  for (int m = 0; m < 1024; ++m) {
    if ((m & 127) == 0) {
#pragma unroll
      for (int q = 0; q < 4; ++q) {
        int f = 1 + q*1024 + m;
        float ph = (float)((n*f) & (FIR_LEN-1)) * (TWO_PI / FIR_LEN);
        sincosf(ph, &s[q], &c[q]);
      }
    }
#pragma unroll
    for (int q = 0; q < 4; ++q) {
      int f = 1 + q*1024 + m;
      if (q < 3 || m < 1023) {
        float2 h = Hs[f];
        acc[q] = fmaf(h.x, c[q], acc[q]);
        acc[q] = fmaf(-h.y, s[q], acc[q]);
      }
      float t = c[q]*cd - s[q]*sd;
      s[q] = s[q]*cd + c[q]*sd;
      c[q] = t;
    }
  }
  float par = (n & 1) ? -1.0f : 1.0f;
  float v = Hs[0].x + Hs[4096].x * par + 2.0f*(acc[0]+acc[1]+acc[2]+acc[3]);
  fir[b*FIR_LEN + n] = v * (1.0f / FIR_LEN);
}

// ---------------------------------------------------------------------------
// K3: pack reversed/zero-padded fir into 8 shifted bf16 copies.
// Gc[b][p][v] = bf16(fir[GTOP - v - p]), zero outside [0,8192).
// ---------------------------------------------------------------------------
#define GTOP 8719
#define GN   8736
__global__ void k_packA(const float* __restrict__ fir, short* __restrict__ Gc) {
  const int b = blockIdx.x >> 3, p = blockIdx.x & 7;
  short* g = Gc + ((size_t)(b*8 + p)) * GN;
  for (int v = threadIdx.x; v < GN; v += 256) {
    int fidx = GTOP - v - p;
    float f = (fidx >= 0 && fidx < FIR_LEN) ? fir[b*FIR_LEN + fidx] : 0.0f;
    g[v] = f2bf(f);
  }
}

// ---------------------------------------------------------------------------
// K4: MFMA convolution (coverage-fixed formulation).
//   o = t0 + 256*In + 16m + i'          (In = 32wv + 16nr + nl)
//   tap t = 16(2s+dl) + i' - jj         (k = 16dl + jj, jj = j0+j)  -- m-free!
//   A[i'][k] = fir[t]                   -> ONE shared 16B frag per step (Gc)
//   B[k][In] = x[t0 + 256In + 16m + jj - 32s - 16dl]  -> per-(m,nr) frag
//   B(m,s+1) == B(m-2,s): two 16-slot rotating B windows (nr=0,1),
//   2 LDS refills each per step; consume m=14,15 first so refill->use
//   distance is 14 MFMAs. slot(m,s) = (m-2s)&15 = (m-2u)&15, static.
// s = 0..256: c=2s+dl covers 0..513 -> taps [i'-15, 8208+i'] ⊇ [0,8191] ∀m.
// ---------------------------------------------------------------------------
#define HPAD   8208
#define WROWS  32768
#define WN     (HPAD + WROWS)          // 40976
#define LXS    42264                   // WN + 8*(WN>>8) + pad
#define NSTEP  256                     // + 1 tail step (s=256)

#define MFMA16(a,bb,c) __builtin_amdgcn_mfma_f32_16x16x32_bf16(a,bb,c,0,0,0)
#define BADDR(r) (2*(r) + (((r) >> 8) << 4))

__global__ __launch_bounds__(256, 1) void k_conv_mfma(
    const float* __restrict__ x, const short* __restrict__ Gc,
    float* __restrict__ y) {
  __shared__ short xs[LXS];
  const int tid = threadIdx.x;
  const int bc = blockIdx.x >> 4, tileIdx = blockIdx.x & 15;
  const int b = bc >> 1;
  const long base = (long)bc * L_SIG;
  const int t0 = tileIdx * WROWS;

  // ---- stage x window (f32 -> bf16), zero history before t=0 ----
  const float* xg = x + base + t0 - HPAD;
  for (int k = tid * 4; k < WN; k += 1024) {
    int g = t0 - HPAD + k;
    float4 v;
    if (g >= 0) {
      v = *(const float4*)(xg + k);
    } else if (g <= -4) {
      v = make_float4(0.f, 0.f, 0.f, 0.f);
    } else {
      v.x = (g + 0 >= 0) ? xg[k + 0] : 0.f;
      v.y = (g + 1 >= 0) ? xg[k + 1] : 0.f;
      v.z = (g + 2 >= 0) ? xg[k + 2] : 0.f;
      v.w = (g + 3 >= 0) ? xg[k + 3] : 0.f;
    }
    int o = k + ((k >> 8) << 3);
    short4 s4 = make_short4(f2bf(v.x), f2bf(v.y), f2bf(v.z), f2bf(v.w));
    *(short4*)(xs + o) = s4;
  }

  // ---- lane geometry ----
  const int wv = tid >> 6, l = tid & 63;
  const int nl = l & 15, h = l >> 4, dl = h >> 1, j0 = (h & 1) * 8;

  // A: shared-frag pointer. frag(s) elem j = fir[16(2s+dl) + nl - j0 - j]
  //    = Gc[p][A0 - p - 16dl - 32s + j] with A0 = GTOP - nl + j0, p = A0&7.
  const int A0 = GTOP - nl + j0;
  const int p = A0 & 7;
  const short* ap = Gc + ((size_t)b * 8 + p) * GN + (A0 - p) - 16 * dl;

  f32x4 acc[16][2];
  const f32x4 z4 = {0.f, 0.f, 0.f, 0.f};
#pragma unroll
  for (int m = 0; m < 16; ++m) { acc[m][0] = z4; acc[m][1] = z4; }

  __syncthreads();

  // B windows: raw idx of frag(m,nr) at step s = rb(nr) + 16m - 32s
  const char* xsb = (const char*)xs;
  int rb0 = HPAD + 256 * (32 * wv + nl) + j0 - 16 * dl;   // nr=0, m=0, s=0
  int rb1 = rb0 + 4096;                                    // nr=1
  bf16x8 bw0[16], bw1[16];
#pragma unroll
  for (int m = 0; m < 16; ++m) {
    int r0 = rb0 + 16 * m, r1 = rb1 + 16 * m;
    bw0[m] = *(const bf16x8*)(xsb + BADDR(r0));
    bw1[m] = *(const bf16x8*)(xsb + BADDR(r1));
  }

  bf16x8 aF = *(const bf16x8*)(ap);     // frag(s=0)
  const short* apn = ap - 32;           // frag(s+1)

  for (int s8 = 0; s8 < NSTEP / 8; ++s8) {
#pragma unroll
    for (int u = 0; u < 8; ++u) {
      // consume the two slots about to be recycled (m=14,15)
      acc[14][0] = MFMA16(aF, bw0[(14 - 2*u) & 15], acc[14][0]);
      acc[14][1] = MFMA16(aF, bw1[(14 - 2*u) & 15], acc[14][1]);
      acc[15][0] = MFMA16(aF, bw0[(15 - 2*u) & 15], acc[15][0]);
      acc[15][1] = MFMA16(aF, bw1[(15 - 2*u) & 15], acc[15][1]);
      // refill with next step's m=0,1 frags (consumed ~14 MFMAs later)
      rb0 -= 32; rb1 -= 32;
      bw0[(14 - 2*u) & 15] = *(const bf16x8*)(xsb + BADDR(rb0));
      bw0[(15 - 2*u) & 15] = *(const bf16x8*)(xsb + BADDR(rb0 + 16));
      bw1[(14 - 2*u) & 15] = *(const bf16x8*)(xsb + BADDR(rb1));
      bw1[(15 - 2*u) & 15] = *(const bf16x8*)(xsb + BADDR(rb1 + 16));
      // next step's shared A frag (global, L2-streamed)
      bf16x8 aN = *(const bf16x8*)(apn);
      apn -= 32;
      // consume m=0..13
#pragma unroll
      for (int m = 0; m < 14; ++m) {
        acc[m][0] = MFMA16(aF, bw0[(m - 2*u) & 15], acc[m][0]);
        acc[m][1] = MFMA16(aF, bw1[(m - 2*u) & 15], acc[m][1]);
      }
      aF = aN;
    }
  }
  // tail step s=256: slot (m-512)&15 = m, window already holds frag(m,256)
#pragma unroll
  for (int m = 0; m < 16; ++m) {
    acc[m][0] = MFMA16(aF, bw0[m], acc[m][0]);
    acc[m][1] = MFMA16(aF, bw1[m], acc[m][1]);
  }

  // ---- epilogue: C col = nl (In), row i' = 4h + r ----
  float* yo = y + base + t0;
#pragma unroll
  for (int m = 0; m < 16; ++m) {
#pragma unroll
    for (int nr = 0; nr < 2; ++nr) {
      int In = 32 * wv + 16 * nr + nl;
      *(f32x4*)(yo + 256 * In + 16 * m + 4 * h) = acc[m][nr];
    }
  }
}

// ---------------------------------------------------------------------------
extern "C" void kernel_launch(void* const* d_in, const int* in_sizes, int n_in,
                              void* d_out, int out_size, void* d_ws, size_t ws_size,
                              hipStream_t stream) {
  const float* x   = (const float*)d_in[0];
  const float* Bs  = (const float*)d_in[1];
  const float* A1p = (const float*)d_in[2];
  const float* A2p = (const float*)d_in[3];
  float* y = (float*)d_out;

  float*  wsf = (float*)d_ws;
  float2* H   = (float2*)wsf;                         // 8*4097 float2
  float*  fir = wsf + 2 * (size_t)NB * NFREQ;         // 8*8192 f32
  short*  Gc  = (short*)(wsf + 2 * (size_t)NB * NFREQ + (size_t)NB * FIR_LEN);

  k_freqresp<<<NB, 256, 0, stream>>>(Bs, A1p, A2p, H);
  k_irfft<<<NB * 32, 256, 0, stream>>>(H, fir);
  k_packA<<<NB * 8, 256, 0, stream>>>(fir, Gc);
  k_conv_mfma<<<NB * NC * (L_SIG / WROWS), 256, 0, stream>>>(x, Gc, y);
}

// Round 5
// 258.545 us; speedup vs baseline: 7.8222x; 1.5589x over previous
//
#include <hip/hip_runtime.h>

#define FIR_LEN 8192
#define NFREQ   4097         // FIR_LEN/2 + 1
#define L_SIG   524288
#define NB      8
#define NC      2
#define NK      6
#define FS      8            // f-slices for irfft partials
#define TWO_PI  6.283185307179586f

typedef __attribute__((ext_vector_type(8))) short bf16x8;
typedef __attribute__((ext_vector_type(4))) float f32x4;

__device__ inline short f2bf(float f) {
  union { float f; unsigned u; } v; v.f = f;
  unsigned u = v.u;
  unsigned r = (u + 0x7fffu + ((u >> 16) & 1u)) >> 16;   // RNE
  return (short)r;
}

// ---------------------------------------------------------------------------
// K1: cascade frequency response H[b][f] (verified)
// ---------------------------------------------------------------------------
__global__ void k_freqresp(const float* __restrict__ Bs,
                           const float* __restrict__ A1p,
                           const float* __restrict__ A2p,
                           float2* __restrict__ H) {
  __shared__ float sb0[NK], sb1[NK], sb2[NK], sa1[NK], sa2[NK];
  const int b = blockIdx.x, tid = threadIdx.x;
  if (tid < NK) {
    sb0[tid] = Bs[(b*NK+tid)*3+0];
    sb1[tid] = Bs[(b*NK+tid)*3+1];
    sb2[tid] = Bs[(b*NK+tid)*3+2];
    float a1 = 2.0f * tanhf(A1p[b*NK+tid]);
    float aa = fabsf(a1);
    sa1[tid] = a1;
    sa2[tid] = ((2.0f - aa) * tanhf(A2p[b*NK+tid]) + aa) * 0.5f;
  }
  __syncthreads();
  for (int f = tid; f < NFREQ; f += blockDim.x) {
    float th = (float)f * (TWO_PI / FIR_LEN);
    float s1, c1;
    sincosf(th, &s1, &c1);
    float c2 = c1*c1 - s1*s1, s2 = 2.0f*s1*c1;
    float hr = 1.0f, hi = 0.0f;
#pragma unroll
    for (int k = 0; k < NK; ++k) {
      float nr = sb0[k] + sb1[k]*c1 + sb2[k]*c2;
      float ni = -(sb1[k]*s1 + sb2[k]*s2);
      float dr = 1.0f + sa1[k]*c1 + sa2[k]*c2;
      float di = -(sa1[k]*s1 + sa2[k]*s2);
      float inv = 1.0f / (dr*dr + di*di);
      float rr = (nr*dr + ni*di) * inv;
      float ri = (ni*dr - nr*di) * inv;
      float t  = hr*rr - hi*ri;
      hi = hr*ri + hi*rr;
      hr = t;
    }
    H[b*NFREQ+f] = make_float2(hr, hi);
  }
}

// ---------------------------------------------------------------------------
// K2a: irfft partial sums. Block = (b, nb, fs): 256 n-values, 512-bin f-slice
//   partial[b][fs][n] = sum_{f=F0}^{F0+511} Hr[f] cos(2pi f n/N) - Hi[f] sin(.)
//   F0 = 1 + 512*fs  (covers f = 1..4096; the f=4096 bin is zeroed at stage
//   time and handled exactly in the reduce kernel).
// 4 rotation streams x 128 steps, sincos only at entry (drift ~1e-5, fine).
// ---------------------------------------------------------------------------
__global__ __launch_bounds__(256) void k_irfft_part(const float2* __restrict__ H,
                                                    float* __restrict__ partial) {
  __shared__ float2 Hs[512];
  const int bid = blockIdx.x;
  const int b  = bid >> 8;          // 32 nb * 8 fs = 256 blocks per b
  const int nb = (bid >> 3) & 31;
  const int fs = bid & 7;
  const int tid = threadIdx.x;
  const int F0 = 1 + 512 * fs;

  for (int i = tid; i < 512; i += 256) {
    float2 v = H[b*NFREQ + F0 + i];
    if (F0 + i == 4096) v = make_float2(0.f, 0.f);   // Nyquist handled in reduce
    Hs[i] = v;
  }
  __syncthreads();

  const int n = nb*256 + tid;
  float sd, cd;
  sincosf((float)n * (TWO_PI / FIR_LEN), &sd, &cd);
  float c[4], s[4], acc[4] = {0.f, 0.f, 0.f, 0.f};
#pragma unroll
  for (int q = 0; q < 4; ++q) {
    int f = F0 + 128*q;
    float ph = (float)((n*f) & (FIR_LEN-1)) * (TWO_PI / FIR_LEN);
    sincosf(ph, &s[q], &c[q]);
  }
#pragma unroll 4
  for (int m = 0; m < 128; ++m) {
#pragma unroll
    for (int q = 0; q < 4; ++q) {
      float2 h = Hs[128*q + m];
      acc[q] = fmaf(h.x, c[q], acc[q]);
      acc[q] = fmaf(-h.y, s[q], acc[q]);
      float t = fmaf(c[q], cd, -(s[q]*sd));
      s[q]    = fmaf(s[q], cd,   c[q]*sd);
      c[q] = t;
    }
  }
  partial[(b*FS + fs)*FIR_LEN + n] = acc[0]+acc[1]+acc[2]+acc[3];
}

// ---------------------------------------------------------------------------
// K2b: reduce partials + DC/Nyquist, scale -> fir
// ---------------------------------------------------------------------------
__global__ __launch_bounds__(256) void k_irfft_red(const float2* __restrict__ H,
                                                   const float* __restrict__ partial,
                                                   float* __restrict__ fir) {
  const int b = blockIdx.x >> 5, nb = blockIdx.x & 31, tid = threadIdx.x;
  const int n = nb*256 + tid;
  float sum = 0.f;
#pragma unroll
  for (int q = 0; q < FS; ++q) sum += partial[(b*FS + q)*FIR_LEN + n];
  float h0 = H[b*NFREQ].x;
  float hN = H[b*NFREQ + 4096].x;
  float par = (n & 1) ? -1.0f : 1.0f;
  fir[b*FIR_LEN + n] = (h0 + hN*par + 2.0f*sum) * (1.0f / FIR_LEN);
}

// ---------------------------------------------------------------------------
// K3: pack reversed/zero-padded fir into 8 shifted bf16 copies.
// Gc[b][p][v] = bf16(fir[GTOP - v - p]), zero outside [0,8192).
// ---------------------------------------------------------------------------
#define GTOP 8719
#define GN   8736
__global__ void k_packA(const float* __restrict__ fir, short* __restrict__ Gc) {
  const int b = blockIdx.x >> 3, p = blockIdx.x & 7;
  short* g = Gc + ((size_t)(b*8 + p)) * GN;
  for (int v = threadIdx.x; v < GN; v += 256) {
    int fidx = GTOP - v - p;
    float f = (fidx >= 0 && fidx < FIR_LEN) ? fir[b*FIR_LEN + fidx] : 0.0f;
    g[v] = f2bf(f);
  }
}

// ---------------------------------------------------------------------------
// K4: MFMA convolution (verified round 4, unchanged).
//   o = t0 + 256*In + 16m + i'          (In = 32wv + 16nr + nl)
//   tap t = 16(2s+dl) + i' - jj         -- m-free A fragment
//   B(m,s+1) == B(m-2,s): two 16-slot rotating B windows, 2 LDS refills each
//   per step, consumed 14 MFMAs after refill. s = 0..256 covers all 8192 taps.
// ---------------------------------------------------------------------------
#define HPAD   8208
#define WROWS  32768
#define WN     (HPAD + WROWS)          // 40976
#define LXS    42264                   // WN + 8*(WN>>8) + pad
#define NSTEP  256                     // + 1 tail step (s=256)

#define MFMA16(a,bb,c) __builtin_amdgcn_mfma_f32_16x16x32_bf16(a,bb,c,0,0,0)
#define BADDR(r) (2*(r) + (((r) >> 8) << 4))

__global__ __launch_bounds__(256, 1) void k_conv_mfma(
    const float* __restrict__ x, const short* __restrict__ Gc,
    float* __restrict__ y) {
  __shared__ short xs[LXS];
  const int tid = threadIdx.x;
  const int bc = blockIdx.x >> 4, tileIdx = blockIdx.x & 15;
  const int b = bc >> 1;
  const long base = (long)bc * L_SIG;
  const int t0 = tileIdx * WROWS;

  // ---- stage x window (f32 -> bf16), zero history before t=0 ----
  const float* xg = x + base + t0 - HPAD;
  for (int k = tid * 4; k < WN; k += 1024) {
    int g = t0 - HPAD + k;
    float4 v;
    if (g >= 0) {
      v = *(const float4*)(xg + k);
    } else if (g <= -4) {
      v = make_float4(0.f, 0.f, 0.f, 0.f);
    } else {
      v.x = (g + 0 >= 0) ? xg[k + 0] : 0.f;
      v.y = (g + 1 >= 0) ? xg[k + 1] : 0.f;
      v.z = (g + 2 >= 0) ? xg[k + 2] : 0.f;
      v.w = (g + 3 >= 0) ? xg[k + 3] : 0.f;
    }
    int o = k + ((k >> 8) << 3);
    short4 s4 = make_short4(f2bf(v.x), f2bf(v.y), f2bf(v.z), f2bf(v.w));
    *(short4*)(xs + o) = s4;
  }

  // ---- lane geometry ----
  const int wv = tid >> 6, l = tid & 63;
  const int nl = l & 15, h = l >> 4, dl = h >> 1, j0 = (h & 1) * 8;

  // A: shared-frag pointer. frag(s) elem j = fir[16(2s+dl) + nl - j0 - j]
  const int A0 = GTOP - nl + j0;
  const int p = A0 & 7;
  const short* ap = Gc + ((size_t)b * 8 + p) * GN + (A0 - p) - 16 * dl;

  f32x4 acc[16][2];
  const f32x4 z4 = {0.f, 0.f, 0.f, 0.f};
#pragma unroll
  for (int m = 0; m < 16; ++m) { acc[m][0] = z4; acc[m][1] = z4; }

  __syncthreads();

  // B windows: raw idx of frag(m,nr) at step s = rb(nr) + 16m - 32s
  const char* xsb = (const char*)xs;
  int rb0 = HPAD + 256 * (32 * wv + nl) + j0 - 16 * dl;   // nr=0, m=0, s=0
  int rb1 = rb0 + 4096;                                    // nr=1
  bf16x8 bw0[16], bw1[16];
#pragma unroll
  for (int m = 0; m < 16; ++m) {
    int r0 = rb0 + 16 * m, r1 = rb1 + 16 * m;
    bw0[m] = *(const bf16x8*)(xsb + BADDR(r0));
    bw1[m] = *(const bf16x8*)(xsb + BADDR(r1));
  }

  bf16x8 aF = *(const bf16x8*)(ap);     // frag(s=0)
  const short* apn = ap - 32;           // frag(s+1)

  for (int s8 = 0; s8 < NSTEP / 8; ++s8) {
#pragma unroll
    for (int u = 0; u < 8; ++u) {
      acc[14][0] = MFMA16(aF, bw0[(14 - 2*u) & 15], acc[14][0]);
      acc[14][1] = MFMA16(aF, bw1[(14 - 2*u) & 15], acc[14][1]);
      acc[15][0] = MFMA16(aF, bw0[(15 - 2*u) & 15], acc[15][0]);
      acc[15][1] = MFMA16(aF, bw1[(15 - 2*u) & 15], acc[15][1]);
      rb0 -= 32; rb1 -= 32;
      bw0[(14 - 2*u) & 15] = *(const bf16x8*)(xsb + BADDR(rb0));
      bw0[(15 - 2*u) & 15] = *(const bf16x8*)(xsb + BADDR(rb0 + 16));
      bw1[(14 - 2*u) & 15] = *(const bf16x8*)(xsb + BADDR(rb1));
      bw1[(15 - 2*u) & 15] = *(const bf16x8*)(xsb + BADDR(rb1 + 16));
      bf16x8 aN = *(const bf16x8*)(apn);
      apn -= 32;
#pragma unroll
      for (int m = 0; m < 14; ++m) {
        acc[m][0] = MFMA16(aF, bw0[(m - 2*u) & 15], acc[m][0]);
        acc[m][1] = MFMA16(aF, bw1[(m - 2*u) & 15], acc[m][1]);
      }
      aF = aN;
    }
  }
  // tail step s=256
#pragma unroll
  for (int m = 0; m < 16; ++m) {
    acc[m][0] = MFMA16(aF, bw0[m], acc[m][0]);
    acc[m][1] = MFMA16(aF, bw1[m], acc[m][1]);
  }

  // ---- epilogue ----
  float* yo = y + base + t0;
#pragma unroll
  for (int m = 0; m < 16; ++m) {
#pragma unroll
    for (int nr = 0; nr < 2; ++nr) {
      int In = 32 * wv + 16 * nr + nl;
      *(f32x4*)(yo + 256 * In + 16 * m + 4 * h) = acc[m][nr];
    }
  }
}

// ---------------------------------------------------------------------------
extern "C" void kernel_launch(void* const* d_in, const int* in_sizes, int n_in,
                              void* d_out, int out_size, void* d_ws, size_t ws_size,
                              hipStream_t stream) {
  const float* x   = (const float*)d_in[0];
  const float* Bs  = (const float*)d_in[1];
  const float* A1p = (const float*)d_in[2];
  const float* A2p = (const float*)d_in[3];
  float* y = (float*)d_out;

  float*  wsf  = (float*)d_ws;
  float2* H    = (float2*)wsf;                              // 65552 f32
  float*  fir  = wsf + 2 * (size_t)NB * NFREQ;              // 65536 f32
  short*  Gc   = (short*)(wsf + 131088);                    // 559104 bf16
  float*  part = wsf + 131088 + 279552;                     // 524288 f32

  k_freqresp<<<NB, 256, 0, stream>>>(Bs, A1p, A2p, H);
  k_irfft_part<<<NB * 32 * FS, 256, 0, stream>>>(H, part);
  k_irfft_red<<<NB * 32, 256, 0, stream>>>(H, part, fir);
  k_packA<<<NB * 8, 256, 0, stream>>>(fir, Gc);
  k_conv_mfma<<<NB * NC * (L_SIG / WROWS), 256, 0, stream>>>(x, Gc, y);
}

// Round 6
// 205.018 us; speedup vs baseline: 9.8645x; 1.2611x over previous
//
#include <hip/hip_runtime.h>

#define FIR_LEN 8192
#define NFREQ   4097         // FIR_LEN/2 + 1
#define L_SIG   524288
#define NB      8
#define NC      2
#define NK      6
#define TWO_PI  6.283185307179586f

typedef __attribute__((ext_vector_type(8))) short bf16x8;
typedef __attribute__((ext_vector_type(4))) float f32x4;

__device__ inline short f2bf(float f) {
  union { float f; unsigned u; } v; v.f = f;
  unsigned u = v.u;
  unsigned r = (u + 0x7fffu + ((u >> 16) & 1u)) >> 16;   // RNE
  return (short)r;
}

// ---------------------------------------------------------------------------
// K1: cascade frequency response H[b][f] (verified)
// ---------------------------------------------------------------------------
__global__ void k_freqresp(const float* __restrict__ Bs,
                           const float* __restrict__ A1p,
                           const float* __restrict__ A2p,
                           float2* __restrict__ H) {
  __shared__ float sb0[NK], sb1[NK], sb2[NK], sa1[NK], sa2[NK];
  const int b = blockIdx.x, tid = threadIdx.x;
  if (tid < NK) {
    sb0[tid] = Bs[(b*NK+tid)*3+0];
    sb1[tid] = Bs[(b*NK+tid)*3+1];
    sb2[tid] = Bs[(b*NK+tid)*3+2];
    float a1 = 2.0f * tanhf(A1p[b*NK+tid]);
    float aa = fabsf(a1);
    sa1[tid] = a1;
    sa2[tid] = ((2.0f - aa) * tanhf(A2p[b*NK+tid]) + aa) * 0.5f;
  }
  __syncthreads();
  for (int f = tid; f < NFREQ; f += blockDim.x) {
    float th = (float)f * (TWO_PI / FIR_LEN);
    float s1, c1;
    sincosf(th, &s1, &c1);
    float c2 = c1*c1 - s1*s1, s2 = 2.0f*s1*c1;
    float hr = 1.0f, hi = 0.0f;
#pragma unroll
    for (int k = 0; k < NK; ++k) {
      float nr = sb0[k] + sb1[k]*c1 + sb2[k]*c2;
      float ni = -(sb1[k]*s1 + sb2[k]*s2);
      float dr = 1.0f + sa1[k]*c1 + sa2[k]*c2;
      float di = -(sa1[k]*s1 + sa2[k]*s2);
      float inv = 1.0f / (dr*dr + di*di);
      float rr = (nr*dr + ni*di) * inv;
      float ri = (ni*dr - nr*di) * inv;
      float t  = hr*rr - hi*ri;
      hi = hr*ri + hi*rr;
      hr = t;
    }
    H[b*NFREQ+f] = make_float2(hr, hi);
  }
}

// ---------------------------------------------------------------------------
// K2a: ifft stage 1 (Cooley-Tukey 64x128, exact f32).
//   Hext[f] = H[f] (f<=4096), conj(H[8192-f]) (f>4096)
//   G[f1][r] = sum_{f2=0}^{63} Hext[128 f2 + f1] * e^{+2pi i f2 r / 64}
// Block = (b, 4 f1-values); wave = one f1 (H loads wave-uniform), lanes = r.
// ---------------------------------------------------------------------------
__global__ __launch_bounds__(256) void k_ifft_s1(const float2* __restrict__ H,
                                                 float2* __restrict__ G) {
  __shared__ float2 tw[64];
  const int tid = threadIdx.x;
  if (tid < 64) {
    float s, c;
    sincosf((float)tid * (TWO_PI / 64.0f), &s, &c);
    tw[tid] = make_float2(c, s);
  }
  __syncthreads();
  const int b = blockIdx.x >> 5;
  const int f1 = (blockIdx.x & 31) * 4 + (tid >> 6);
  const int r = tid & 63;
  const float2* Hb = H + b * NFREQ;

  float Gr = 0.f, Gi = 0.f;
#pragma unroll 4
  for (int f2 = 0; f2 < 64; ++f2) {
    int f = 128 * f2 + f1;
    int neg = f > 4096;
    int fi = neg ? 8192 - f : f;
    float2 h = Hb[fi];
    float hi = neg ? -h.y : h.y;
    float2 w = tw[(f2 * r) & 63];
    Gr = fmaf(h.x, w.x, Gr); Gr = fmaf(-hi, w.y, Gr);
    Gi = fmaf(h.x, w.y, Gi); Gi = fmaf( hi, w.x, Gi);
  }
  G[(b * 128 + f1) * 64 + r] = make_float2(Gr, Gi);
}

// ---------------------------------------------------------------------------
// K2b: ifft stage 2.
//   fir[n] = (1/8192) * Re{ sum_{f1=0}^{127} G[f1][n&63] e^{+2pi i f1 n/8192} }
// G staged in 64KB LDS (lanes read consecutive r -> conflict-free).
// 4 rotation streams x 32 steps, exact integer entry phases.
// ---------------------------------------------------------------------------
__global__ __launch_bounds__(256) void k_ifft_s2(const float2* __restrict__ G,
                                                 float* __restrict__ fir) {
  __shared__ float2 Gs[8192];
  const int b = blockIdx.x >> 5, nblk = blockIdx.x & 31, tid = threadIdx.x;
  for (int i = tid; i < 8192; i += 256) Gs[i] = G[b * 8192 + i];
  __syncthreads();

  const int n = nblk * 256 + tid;
  const int r = n & 63;
  float sd, cd;
  sincosf((float)n * (TWO_PI / FIR_LEN), &sd, &cd);
  float c[4], s[4], acc[4] = {0.f, 0.f, 0.f, 0.f};
#pragma unroll
  for (int q = 0; q < 4; ++q) {
    float ph = (float)((n * (32 * q)) & (FIR_LEN - 1)) * (TWO_PI / FIR_LEN);
    sincosf(ph, &s[q], &c[q]);
  }
#pragma unroll 4
  for (int mm = 0; mm < 32; ++mm) {
#pragma unroll
    for (int q = 0; q < 4; ++q) {
      float2 g = Gs[((q * 32 + mm) << 6) + r];
      acc[q] = fmaf(g.x, c[q], acc[q]);
      acc[q] = fmaf(-g.y, s[q], acc[q]);
      float t = fmaf(c[q], cd, -(s[q] * sd));
      s[q]    = fmaf(s[q], cd,   c[q] * sd);
      c[q] = t;
    }
  }
  fir[b * FIR_LEN + n] = (acc[0] + acc[1] + acc[2] + acc[3]) * (1.0f / FIR_LEN);
}

// ---------------------------------------------------------------------------
// K3: pack reversed/zero-padded fir into 8 shifted bf16 copies.
// Gc[b][p][v] = bf16(fir[GTOP - v - p]), zero outside [0,8192).
// ---------------------------------------------------------------------------
#define GTOP 8719
#define GN   8736
__global__ void k_packA(const float* __restrict__ fir, short* __restrict__ Gc) {
  const int b = blockIdx.x >> 3, p = blockIdx.x & 7;
  short* g = Gc + ((size_t)(b*8 + p)) * GN;
  for (int v = threadIdx.x; v < GN; v += 256) {
    int fidx = GTOP - v - p;
    float f = (fidx >= 0 && fidx < FIR_LEN) ? fir[b*FIR_LEN + fidx] : 0.0f;
    g[v] = f2bf(f);
  }
}

// ---------------------------------------------------------------------------
// K4: MFMA convolution — 8-wave blocks (2 waves/SIMD) for latency hiding.
//   o = t0 + 256*In + 16m + i'          (In = 16wv + nl, wv in [0,8))
//   tap t = 16(2s+dl) + i' - jj         -- m-free A fragment (Gc, L2/L3-hot)
//   B(m,s+1) == B(m-2,s): one 16-slot rotating B window per wave,
//   2 LDS refills/step, consumed 14 MFMAs after refill. 257 steps = all taps.
// ---------------------------------------------------------------------------
#define HPAD   8208
#define WROWS  32768
#define WN     (HPAD + WROWS)          // 40976
#define LXS    42264                   // WN + 8*(WN>>8) + pad
#define NSTEP  256                     // + 1 tail step (s=256)

#define MFMA16(a,bb,c) __builtin_amdgcn_mfma_f32_16x16x32_bf16(a,bb,c,0,0,0)
#define BADDR(r) (2*(r) + (((r) >> 8) << 4))

__global__ __launch_bounds__(512, 2) void k_conv_mfma(
    const float* __restrict__ x, const short* __restrict__ Gc,
    float* __restrict__ y) {
  __shared__ short xs[LXS];
  const int tid = threadIdx.x;
  const int bc = blockIdx.x >> 4, tileIdx = blockIdx.x & 15;
  const int b = bc >> 1;
  const long base = (long)bc * L_SIG;
  const int t0 = tileIdx * WROWS;

  // ---- stage x window (f32 -> bf16), zero history before t=0 ----
  const float* xg = x + base + t0 - HPAD;
  for (int k = tid * 4; k < WN; k += 2048) {
    int g = t0 - HPAD + k;
    float4 v;
    if (g >= 0) {
      v = *(const float4*)(xg + k);
    } else if (g <= -4) {
      v = make_float4(0.f, 0.f, 0.f, 0.f);
    } else {
      v.x = (g + 0 >= 0) ? xg[k + 0] : 0.f;
      v.y = (g + 1 >= 0) ? xg[k + 1] : 0.f;
      v.z = (g + 2 >= 0) ? xg[k + 2] : 0.f;
      v.w = (g + 3 >= 0) ? xg[k + 3] : 0.f;
    }
    int o = k + ((k >> 8) << 3);
    short4 s4 = make_short4(f2bf(v.x), f2bf(v.y), f2bf(v.z), f2bf(v.w));
    *(short4*)(xs + o) = s4;
  }

  // ---- lane geometry ----
  const int wv = tid >> 6, l = tid & 63;
  const int nl = l & 15, h = l >> 4, dl = h >> 1, j0 = (h & 1) * 8;
  const int In = 16 * wv + nl;           // output column, [0,128)

  // A: shared-frag pointer. frag(s) elem j = fir[16(2s+dl) + nl - j0 - j]
  const int A0 = GTOP - nl + j0;
  const int p = A0 & 7;
  const short* ap = Gc + ((size_t)b * 8 + p) * GN + (A0 - p) - 16 * dl;

  f32x4 acc[16];
  const f32x4 z4 = {0.f, 0.f, 0.f, 0.f};
#pragma unroll
  for (int m = 0; m < 16; ++m) acc[m] = z4;

  __syncthreads();

  // B window: raw idx of frag(m) at step s = rb + 16m - 32s
  const char* xsb = (const char*)xs;
  int rb = HPAD + 256 * In + j0 - 16 * dl;
  bf16x8 bw[16];
#pragma unroll
  for (int m = 0; m < 16; ++m) {
    int r0 = rb + 16 * m;
    bw[m] = *(const bf16x8*)(xsb + BADDR(r0));
  }

  bf16x8 aF = *(const bf16x8*)(ap);     // frag(s=0)
  const short* apn = ap - 32;           // frag(s+1)

  for (int s8 = 0; s8 < NSTEP / 8; ++s8) {
#pragma unroll
    for (int u = 0; u < 8; ++u) {
      // consume the two slots about to be recycled (m=14,15)
      acc[14] = MFMA16(aF, bw[(14 - 2*u) & 15], acc[14]);
      acc[15] = MFMA16(aF, bw[(15 - 2*u) & 15], acc[15]);
      // refill with next step's m=0,1 frags (consumed 14 MFMAs later)
      rb -= 32;
      bw[(14 - 2*u) & 15] = *(const bf16x8*)(xsb + BADDR(rb));
      bw[(15 - 2*u) & 15] = *(const bf16x8*)(xsb + BADDR(rb + 16));
      // next step's shared A frag (global, L2/L3-hot)
      bf16x8 aN = *(const bf16x8*)(apn);
      apn -= 32;
#pragma unroll
      for (int m = 0; m < 14; ++m)
        acc[m] = MFMA16(aF, bw[(m - 2*u) & 15], acc[m]);
      aF = aN;
    }
  }
  // tail step s=256: slot (m-512)&15 = m
#pragma unroll
  for (int m = 0; m < 16; ++m) acc[m] = MFMA16(aF, bw[m], acc[m]);

  // ---- epilogue: C col = nl (In), row i' = 4h + reg ----
  float* yo = y + base + t0;
#pragma unroll
  for (int m = 0; m < 16; ++m)
    *(f32x4*)(yo + 256 * In + 16 * m + 4 * h) = acc[m];
}

// ---------------------------------------------------------------------------
extern "C" void kernel_launch(void* const* d_in, const int* in_sizes, int n_in,
                              void* d_out, int out_size, void* d_ws, size_t ws_size,
                              hipStream_t stream) {
  const float* x   = (const float*)d_in[0];
  const float* Bs  = (const float*)d_in[1];
  const float* A1p = (const float*)d_in[2];
  const float* A2p = (const float*)d_in[3];
  float* y = (float*)d_out;

  float*  wsf = (float*)d_ws;
  float2* H   = (float2*)wsf;                    // 65552 f32
  float*  fir = wsf + 65552;                     // 65536 f32
  short*  Gc  = (short*)(wsf + 131088);          // 559104 bf16 (16B-aligned)
  float2* G   = (float2*)(wsf + 410640);         // 8*128*64 float2

  k_freqresp<<<NB, 256, 0, stream>>>(Bs, A1p, A2p, H);
  k_ifft_s1<<<NB * 32, 256, 0, stream>>>(H, G);
  k_ifft_s2<<<NB * 32, 256, 0, stream>>>(G, fir);
  k_packA<<<NB * 8, 256, 0, stream>>>(fir, Gc);
  k_conv_mfma<<<NB * NC * (L_SIG / WROWS), 512, 0, stream>>>(x, Gc, y);
}

// Round 7
// 193.528 us; speedup vs baseline: 10.4502x; 1.0594x over previous
//
#include <hip/hip_runtime.h>

#define FIR_LEN 8192
#define NFREQ   4097
#define L_SIG   524288
#define NB      8
#define NC      2
#define NK      6
#define TWO_PI  6.283185307179586f

typedef __attribute__((ext_vector_type(8))) short bf16x8;
typedef __attribute__((ext_vector_type(4))) float f32x4;

__device__ inline short f2bf(float f) {
  union { float f; unsigned u; } v; v.f = f;
  unsigned u = v.u;
  unsigned r = (u + 0x7fffu + ((u >> 16) & 1u)) >> 16;   // RNE
  return (short)r;
}

// ---------------------------------------------------------------------------
// K1: fused coefficient-activation + cascade DTFT + ifft stage 1 (CT 64x128).
//   H(f) = prod_k (b0+b1 w+b2 w^2)/(1+a1 w+a2 w^2), w = e^{-2pi i f/8192}
//   (real coeffs => H(8192-f) = conj H(f) automatically; evaluate f in [0,8192))
//   G[f1][r] = sum_{f2<64} H(128 f2 + f1) * e^{+2pi i f2 r/64}
// Block = (b, 4 f1-values): thread (f1l,f2) evaluates one H bin into LDS;
// then wave f1l computes G[f1][r=lane] (H reads wave-uniform, tw per-lane).
// ---------------------------------------------------------------------------
__global__ __launch_bounds__(256) void k_ifft_s1(const float* __restrict__ Bs,
                                                 const float* __restrict__ A1p,
                                                 const float* __restrict__ A2p,
                                                 float2* __restrict__ G) {
  __shared__ float sb0[NK], sb1[NK], sb2[NK], sa1[NK], sa2[NK];
  __shared__ float2 Hs[256];
  __shared__ float2 tw[64];
  const int tid = threadIdx.x;
  const int b = blockIdx.x >> 5;
  const int f1base = (blockIdx.x & 31) * 4;

  if (tid < NK) {
    sb0[tid] = Bs[(b*NK+tid)*3+0];
    sb1[tid] = Bs[(b*NK+tid)*3+1];
    sb2[tid] = Bs[(b*NK+tid)*3+2];
    float a1 = 2.0f * tanhf(A1p[b*NK+tid]);
    float aa = fabsf(a1);
    sa1[tid] = a1;
    sa2[tid] = ((2.0f - aa) * tanhf(A2p[b*NK+tid]) + aa) * 0.5f;
  }
  if (tid < 64) {
    float s, c;
    sincosf((float)tid * (TWO_PI / 64.0f), &s, &c);
    tw[tid] = make_float2(c, s);
  }
  __syncthreads();

  // ---- per-thread H bin: f = 128*f2 + f1 ----
  {
    const int f1l = tid >> 6, f2 = tid & 63;
    const int f = 128 * f2 + f1base + f1l;
    float th = (float)f * (TWO_PI / FIR_LEN);
    float s1, c1;
    sincosf(th, &s1, &c1);
    float c2 = c1*c1 - s1*s1, s2 = 2.0f*s1*c1;
    float hr = 1.0f, hi = 0.0f;
#pragma unroll
    for (int k = 0; k < NK; ++k) {
      float nr = sb0[k] + sb1[k]*c1 + sb2[k]*c2;
      float ni = -(sb1[k]*s1 + sb2[k]*s2);
      float dr = 1.0f + sa1[k]*c1 + sa2[k]*c2;
      float di = -(sa1[k]*s1 + sa2[k]*s2);
      float inv = 1.0f / (dr*dr + di*di);
      float rr = (nr*dr + ni*di) * inv;
      float ri = (ni*dr - nr*di) * inv;
      float t  = hr*rr - hi*ri;
      hi = hr*ri + hi*rr;
      hr = t;
    }
    Hs[tid] = make_float2(hr, hi);
  }
  __syncthreads();

  // ---- G sum: wave = one f1, lanes = r ----
  const int f1l = tid >> 6, r = tid & 63;
  float Gr = 0.f, Gi = 0.f;
#pragma unroll 4
  for (int f2 = 0; f2 < 64; ++f2) {
    float2 h = Hs[64 * f1l + f2];            // wave-uniform broadcast
    float2 w = tw[(f2 * r) & 63];
    Gr = fmaf(h.x, w.x, Gr); Gr = fmaf(-h.y, w.y, Gr);
    Gi = fmaf(h.x, w.y, Gi); Gi = fmaf( h.y, w.x, Gi);
  }
  G[((size_t)b * 128 + f1base + f1l) * 64 + r] = make_float2(Gr, Gi);
}

// ---------------------------------------------------------------------------
// K2: ifft stage 2 fused with packA.
//   fir[n] = (1/8192) Re{ sum_{f1<128} G[f1][n&63] e^{+2pi i f1 n/8192} }
//   Gc[b][p][v] = bf16(fir[GTOP - v - p]), zero outside the mapped range.
// ---------------------------------------------------------------------------
#define GTOP 8719
#define GN   8736
__global__ __launch_bounds__(256) void k_ifft_s2(const float2* __restrict__ G,
                                                 short* __restrict__ Gc) {
  __shared__ float2 Gs[8192];
  const int b = blockIdx.x >> 5, nblk = blockIdx.x & 31, tid = threadIdx.x;
  for (int i = tid; i < 8192; i += 256) Gs[i] = G[(size_t)b * 8192 + i];
  __syncthreads();

  const int n = nblk * 256 + tid;
  const int r = n & 63;
  float sd, cd;
  sincosf((float)n * (TWO_PI / FIR_LEN), &sd, &cd);
  float c[4], s[4], acc[4] = {0.f, 0.f, 0.f, 0.f};
#pragma unroll
  for (int q = 0; q < 4; ++q) {
    float ph = (float)((n * (32 * q)) & (FIR_LEN - 1)) * (TWO_PI / FIR_LEN);
    sincosf(ph, &s[q], &c[q]);
  }
#pragma unroll 4
  for (int mm = 0; mm < 32; ++mm) {
#pragma unroll
    for (int q = 0; q < 4; ++q) {
      float2 g = Gs[((q * 32 + mm) << 6) + r];
      acc[q] = fmaf(g.x, c[q], acc[q]);
      acc[q] = fmaf(-g.y, s[q], acc[q]);
      float t = fmaf(c[q], cd, -(s[q] * sd));
      s[q]    = fmaf(s[q], cd,   c[q] * sd);
      c[q] = t;
    }
  }
  const short bv = f2bf((acc[0] + acc[1] + acc[2] + acc[3]) * (1.0f / FIR_LEN));
  short* gb = Gc + (size_t)b * 8 * GN;
#pragma unroll
  for (int p = 0; p < 8; ++p)
    gb[p * GN + (GTOP - n - p)] = bv;

  if (nblk == 0) {  // zero pad: head v < 528-p, tail v > 8719-p (ws is poisoned)
#pragma unroll
    for (int p = 0; p < 8; ++p) {
      for (int v = tid; v < 528 - p; v += 256) gb[p * GN + v] = 0;
      if (tid < 16 + p) gb[p * GN + 8720 - p + tid] = 0;
    }
  }
}

// ---------------------------------------------------------------------------
// K3: MFMA convolution — 16384-tile, 8 waves = 4 col-groups x 2 m-halves.
//   o = t0 + 256*In + 16m + i'   (In = 16*(wv&3)+nl, m = 8*(wv>>2)+mm)
//   tap t = 16(2s+dl) + i' - jj  -- m-free A fragment, shared by all waves
//   B(m,s+1) == B(m-2,s): 8-slot rotating B window, 2 LDS refills/step,
//   A prefetched 2 steps deep. 257 steps cover all 8192 taps (zero-padded Gc).
// ~49.6KB LDS -> 2-3 blocks/CU = 4-6 waves/SIMD for latency hiding.
// ---------------------------------------------------------------------------
#define HPAD   8208
#define WROWS  16384
#define WN     (HPAD + WROWS)          // 24592
#define LXS    25368                   // WN + 8*(WN>>8) + slack (shorts)
#define NSTEP  256                     // + 1 tail step (s=256)

#define MFMA16(a,bb,c) __builtin_amdgcn_mfma_f32_16x16x32_bf16(a,bb,c,0,0,0)
#define BADDR(r) (2*(r) + (((r) >> 8) << 4))

__global__ __launch_bounds__(512, 4) void k_conv_mfma(
    const float* __restrict__ x, const short* __restrict__ Gc,
    float* __restrict__ y) {
  __shared__ short xs[LXS];
  const int tid = threadIdx.x;
  const int bc = blockIdx.x >> 5, tileIdx = blockIdx.x & 31;
  const int b = bc >> 1;
  const long base = (long)bc * L_SIG;
  const int t0 = tileIdx * WROWS;

  // ---- stage x window (f32 -> bf16), zero history before t=0 ----
  const float* xg = x + base + t0 - HPAD;
  for (int k = tid * 4; k < WN; k += 2048) {
    int g = t0 - HPAD + k;
    float4 v;
    if (g >= 0) {
      v = *(const float4*)(xg + k);
    } else if (g <= -4) {
      v = make_float4(0.f, 0.f, 0.f, 0.f);
    } else {
      v.x = (g + 0 >= 0) ? xg[k + 0] : 0.f;
      v.y = (g + 1 >= 0) ? xg[k + 1] : 0.f;
      v.z = (g + 2 >= 0) ? xg[k + 2] : 0.f;
      v.w = (g + 3 >= 0) ? xg[k + 3] : 0.f;
    }
    int o = k + ((k >> 8) << 3);
    short4 s4 = make_short4(f2bf(v.x), f2bf(v.y), f2bf(v.z), f2bf(v.w));
    *(short4*)(xs + o) = s4;
  }

  // ---- lane geometry ----
  const int wv = tid >> 6, l = tid & 63;
  const int nl = l & 15, h = l >> 4, dl = h >> 1, j0 = (h & 1) * 8;
  const int In = 16 * (wv & 3) + nl;     // output column, [0,64)
  const int mbase = 8 * (wv >> 2);       // m-half: 0 or 8

  // A: shared-frag pointer. frag(s) elem j = fir[16(2s+dl) + nl - j0 - j]
  const int A0 = GTOP - nl + j0;
  const int p = A0 & 7;
  const short* ap = Gc + ((size_t)b * 8 + p) * GN + (A0 - p) - 16 * dl;

  f32x4 acc[8];
  const f32x4 z4 = {0.f, 0.f, 0.f, 0.f};
#pragma unroll
  for (int mm = 0; mm < 8; ++mm) acc[mm] = z4;

  bf16x8 aF = *(const bf16x8*)(ap);        // frag(0)
  bf16x8 aN = *(const bf16x8*)(ap - 32);   // frag(1)
  const short* apn = ap - 64;              // frag(2)

  __syncthreads();

  // B window: slot(mm,s) = (mm-2s)&7; raw idx of frag(mbase+mm) = rb0+16mm-32s
  const char* xsb = (const char*)xs;
  int rb = HPAD + 256 * In + 16 * mbase + j0 - 16 * dl;
  bf16x8 bw[8];
#pragma unroll
  for (int mm = 0; mm < 8; ++mm) {
    int r0 = rb + 16 * mm;
    bw[mm] = *(const bf16x8*)(xsb + BADDR(r0));
  }

  for (int s4i = 0; s4i < NSTEP / 4; ++s4i) {
#pragma unroll
    for (int u = 0; u < 4; ++u) {
      // consume the two slots about to be recycled (mm=6,7)
      acc[6] = MFMA16(aF, bw[(6 - 2*u) & 7], acc[6]);
      acc[7] = MFMA16(aF, bw[(7 - 2*u) & 7], acc[7]);
      // refill with next step's mm=0,1 frags
      rb -= 32;
      bw[(6 - 2*u) & 7] = *(const bf16x8*)(xsb + BADDR(rb));
      bw[(7 - 2*u) & 7] = *(const bf16x8*)(xsb + BADDR(rb + 16));
      // A prefetch, 2 steps deep
      bf16x8 aN2 = *(const bf16x8*)(apn);
      apn -= 32;
#pragma unroll
      for (int mm = 0; mm < 6; ++mm)
        acc[mm] = MFMA16(aF, bw[(mm - 2*u) & 7], acc[mm]);
      aF = aN;
      aN = aN2;
    }
  }
  // tail step s=256: slot (mm-512)&7 = mm
#pragma unroll
  for (int mm = 0; mm < 8; ++mm) acc[mm] = MFMA16(aF, bw[mm], acc[mm]);

  // ---- epilogue: C col = nl (In), row i' = 4h + reg ----
  float* yo = y + base + t0;
#pragma unroll
  for (int mm = 0; mm < 8; ++mm)
    *(f32x4*)(yo + 256 * In + 16 * (mbase + mm) + 4 * h) = acc[mm];
}

// ---------------------------------------------------------------------------
extern "C" void kernel_launch(void* const* d_in, const int* in_sizes, int n_in,
                              void* d_out, int out_size, void* d_ws, size_t ws_size,
                              hipStream_t stream) {
  const float* x   = (const float*)d_in[0];
  const float* Bs  = (const float*)d_in[1];
  const float* A1p = (const float*)d_in[2];
  const float* A2p = (const float*)d_in[3];
  float* y = (float*)d_out;

  short*  Gc = (short*)d_ws;                                   // 8*8*8736 bf16
  float2* G  = (float2*)((char*)d_ws + (size_t)NB*8*GN*2);     // 8*128*64 c64

  k_ifft_s1<<<NB * 32, 256, 0, stream>>>(Bs, A1p, A2p, G);
  k_ifft_s2<<<NB * 32, 256, 0, stream>>>(G, Gc);
  k_conv_mfma<<<NB * NC * (L_SIG / WROWS), 512, 0, stream>>>(x, Gc, y);
}